// Round 5
// baseline (99.589 us; speedup 1.0000x reference)
//
#include <hip/hip_runtime.h>
#include <math.h>

#define M 1920        // K*N rows
#define DIMS 512
#define KGRP 128
#define NGRP 15
#define NQ 32         // quads of 4 groups
#define KC 32         // k-chunk = one MFMA K-step
#define NTILES 528    // NQ*(NQ+1)/2
#define SPAD 40       // staging row stride in shorts: 80 B -> 20 banks, 2-way max, 16B-aligned

typedef __attribute__((ext_vector_type(8))) short bf16x8;
typedef __attribute__((ext_vector_type(4))) float f32x4;

#define MFMA(A, B, C) __builtin_amdgcn_mfma_f32_16x16x32_bf16(A, B, C, 0, 0, 0)

// exact split: x = hi + lo + eps, |eps| <= ~2^-16 |x|
__device__ inline void split2(float x, short& h, short& l) {
    unsigned u = __float_as_uint(x);
    h = (short)(u >> 16);                              // truncated bf16
    float fl = x - __uint_as_float(u & 0xFFFF0000u);   // exact residual
    l = (short)(__float_as_uint(fl) >> 16);
}

// ---------------- per-group: dAA[a][15*15] blocks + row sq-norms (fp32 exact) ----------------
__global__ __launch_bounds__(256) void daa_norm_kernel(const float* __restrict__ E,
                                                       float* __restrict__ dAAg,
                                                       float* __restrict__ sqn) {
    const int a = blockIdx.x;
    const int t = threadIdx.x;
    __shared__ float Ash[NGRP][516];
    const float4* Ea = reinterpret_cast<const float4*>(E + (size_t)a * NGRP * DIMS);
    for (int e = t; e < NGRP * (DIMS / 4); e += 256) {
        int r = e / (DIMS / 4), c4 = e % (DIMS / 4);
        *reinterpret_cast<float4*>(&Ash[r][c4 * 4]) = Ea[r * (DIMS / 4) + c4];
    }
    __syncthreads();
    if (t < NGRP * NGRP) {
        int i = t / NGRP, j = t % NGRP;
        float s = 0.0f;
        #pragma unroll 4
        for (int k = 0; k < DIMS; k += 4) {
            float4 ai = *reinterpret_cast<const float4*>(&Ash[i][k]);
            float4 aj = *reinterpret_cast<const float4*>(&Ash[j][k]);
            float dx = ai.x - aj.x, dy = ai.y - aj.y, dz = ai.z - aj.z, dw = ai.w - aj.w;
            s = fmaf(dx, dx, s); s = fmaf(dy, dy, s);
            s = fmaf(dz, dz, s); s = fmaf(dw, dw, s);
        }
        dAAg[a * 225 + t] = sqrtf(s);
    } else if (t >= 240 && t < 240 + NGRP) {
        int i = t - 240;
        float s = 0.0f;
        #pragma unroll 4
        for (int k = 0; k < DIMS; k += 4) {
            float4 ai = *reinterpret_cast<const float4*>(&Ash[i][k]);
            s = fmaf(ai.x, ai.x, s); s = fmaf(ai.y, ai.y, s);
            s = fmaf(ai.z, ai.z, s); s = fmaf(ai.w, ai.w, s);
        }
        sqn[a * NGRP + i] = s;
    }
}

// ---------------- quad tile via split-bf16 MFMA + fused margin ----------------
__global__ __launch_bounds__(256) void quad_kernel(const float* __restrict__ E,
                                                   const float* __restrict__ sqn,
                                                   const float* __restrict__ dAAg,
                                                   float* __restrict__ acc) {
    // decode blockIdx -> (qa, qb), qa <= qb
    int qa = 0, rem = blockIdx.x;
    while (rem >= NQ - qa) { rem -= NQ - qa; ++qa; }
    const int qb = qa + rem;

    __shared__ short Ah[64][SPAD], Al[64][SPAD], Bh[64][SPAD], Bl[64][SPAD];
    __shared__ float Dt[64][68];
    __shared__ float dAAc[4][228];
    __shared__ float sqnA[64], sqnB[64];
    __shared__ unsigned char ijt[105][2];
    __shared__ float wred[4];

    const int t = threadIdx.x;
    const int row0 = qa * 60, col0 = qb * 60;

    for (int e = t; e < 900; e += 256)
        dAAc[e / 225][e % 225] = dAAg[(qa * 4 + e / 225) * 225 + e % 225];
    if (t < 64) {
        sqnA[t] = sqn[row0 + min(t, 59)];
        sqnB[t] = sqn[col0 + min(t, 59)];
    }
    if (t < 105) {
        int i = 0, r2 = t;
        while (r2 >= 14 - i) { r2 -= 14 - i; ++i; }
        ijt[t][0] = (unsigned char)i;
        ijt[t][1] = (unsigned char)(i + 1 + r2);
    }

    const int wv = t >> 6, lane = t & 63;
    const int lr = lane & 15, lk = (lane >> 4) * 8;   // frag row/col, k-offset

    // staging assignment: thread -> (row 0..63, k-quad 0/8/16/24)
    const int srow = t >> 2;
    const int skq = (t & 3) * 8;
    const float* pA = &E[(size_t)(row0 + min(srow, 59)) * DIMS + skq];
    const float* pB = &E[(size_t)(col0 + min(srow, 59)) * DIMS + skq];

    f32x4 z4 = {0.f, 0.f, 0.f, 0.f};
    f32x4 c0 = z4, c1 = z4, c2 = z4, c3 = z4;

    for (int k0 = 0; k0 < DIMS; k0 += KC) {
        __syncthreads();   // previous chunk's readers done before overwrite
        {
            float4 va0 = *reinterpret_cast<const float4*>(pA + k0);
            float4 va1 = *reinterpret_cast<const float4*>(pA + k0 + 4);
            float4 vb0 = *reinterpret_cast<const float4*>(pB + k0);
            float4 vb1 = *reinterpret_cast<const float4*>(pB + k0 + 4);
            float xa[8] = {va0.x, va0.y, va0.z, va0.w, va1.x, va1.y, va1.z, va1.w};
            float xb[8] = {vb0.x, vb0.y, vb0.z, vb0.w, vb1.x, vb1.y, vb1.z, vb1.w};
            bf16x8 ah, al, bh, bl;
            #pragma unroll
            for (int i = 0; i < 8; ++i) {
                short h, l;
                split2(xa[i], h, l); ah[i] = h; al[i] = l;
                split2(xb[i], h, l); bh[i] = h; bl[i] = l;
            }
            *reinterpret_cast<bf16x8*>(&Ah[srow][skq]) = ah;
            *reinterpret_cast<bf16x8*>(&Al[srow][skq]) = al;
            *reinterpret_cast<bf16x8*>(&Bh[srow][skq]) = bh;
            *reinterpret_cast<bf16x8*>(&Bl[srow][skq]) = bl;
        }
        __syncthreads();
        // fragments: wave wv owns tile rows [16wv,16wv+16); 4 col-tiles
        bf16x8 a_h = *reinterpret_cast<const bf16x8*>(&Ah[(wv << 4) + lr][lk]);
        bf16x8 a_l = *reinterpret_cast<const bf16x8*>(&Al[(wv << 4) + lr][lk]);
        bf16x8 b_h0 = *reinterpret_cast<const bf16x8*>(&Bh[lr][lk]);
        bf16x8 b_l0 = *reinterpret_cast<const bf16x8*>(&Bl[lr][lk]);
        bf16x8 b_h1 = *reinterpret_cast<const bf16x8*>(&Bh[16 + lr][lk]);
        bf16x8 b_l1 = *reinterpret_cast<const bf16x8*>(&Bl[16 + lr][lk]);
        bf16x8 b_h2 = *reinterpret_cast<const bf16x8*>(&Bh[32 + lr][lk]);
        bf16x8 b_l2 = *reinterpret_cast<const bf16x8*>(&Bl[32 + lr][lk]);
        bf16x8 b_h3 = *reinterpret_cast<const bf16x8*>(&Bh[48 + lr][lk]);
        bf16x8 b_l3 = *reinterpret_cast<const bf16x8*>(&Bl[48 + lr][lk]);
        c0 = MFMA(a_l, b_h0, c0); c0 = MFMA(a_h, b_l0, c0); c0 = MFMA(a_h, b_h0, c0);
        c1 = MFMA(a_l, b_h1, c1); c1 = MFMA(a_h, b_l1, c1); c1 = MFMA(a_h, b_h1, c1);
        c2 = MFMA(a_l, b_h2, c2); c2 = MFMA(a_h, b_l2, c2); c2 = MFMA(a_h, b_h2, c2);
        c3 = MFMA(a_l, b_h3, c3); c3 = MFMA(a_h, b_l3, c3); c3 = MFMA(a_h, b_h3, c3);
    }

    // epilogue: C/D layout col=lane&15, row=(lane>>4)*4+reg  [m89]
    {
        const int rbase = (wv << 4) + ((lane >> 4) << 2);
        #define EPI(J, CJ)                                                    \
        {   _Pragma("unroll")                                                 \
            for (int r = 0; r < 4; ++r) {                                     \
                int rr = rbase + r;                                           \
                int cc = (J << 4) + lr;                                       \
                float sq = sqnA[rr] + sqnB[cc] - 2.0f * CJ[r];                \
                Dt[rr][cc] = sqrtf(fmaxf(sq, 0.0f));                          \
            }                                                                 \
        }
        EPI(0, c0) EPI(1, c1) EPI(2, c2) EPI(3, c3)
        #undef EPI
    }
    __syncthreads();

    // fused margin: pairs (a,b) = (qa*4+pa, qb*4+pb) with a < b
    float v = 0.0f;
    for (int it = t; it < 16 * 105; it += 256) {
        int p16 = it / 105, r2 = it % 105;
        int pa = p16 >> 2, pb = p16 & 3;
        int a = qa * 4 + pa, b = qb * 4 + pb;
        if (a < b) {
            int i = ijt[r2][0], j = ijt[r2][1];
            float base = dAAc[pa][i * 15 + j] + 1.5f;
            const float* drow = &Dt[pa * 15 + i][pb * 15];
            #pragma unroll
            for (int l = 0; l < NGRP; ++l) v += fmaxf(base - drow[l], 0.0f);
        }
    }
    #pragma unroll
    for (int off = 32; off > 0; off >>= 1) v += __shfl_down(v, off);
    if ((t & 63) == 0) wred[t >> 6] = v;
    __syncthreads();
    if (t == 0) atomicAdd(acc, wred[0] + wred[1] + wred[2] + wred[3]);
}

// ---------------- per-group radius (fp32 exact) ----------------
__global__ __launch_bounds__(256) void radius_kernel(const float* __restrict__ E,
                                                     float* __restrict__ md) {
    const int g = blockIdx.x;
    const int t = threadIdx.x;
    __shared__ float cent[DIMS];
    __shared__ float ws4[4];
    float c0 = 0.0f, c1 = 0.0f;
    #pragma unroll
    for (int m = 0; m < NGRP; ++m) {
        c0 += E[(size_t)(g * NGRP + m) * DIMS + t];
        c1 += E[(size_t)(g * NGRP + m) * DIMS + t + 256];
    }
    cent[t]       = c0 / (float)NGRP;
    cent[t + 256] = c1 / (float)NGRP;
    __syncthreads();
    float sumd = 0.0f;
    for (int m = 0; m < NGRP; ++m) {
        float d0 = E[(size_t)(g * NGRP + m) * DIMS + t]       - cent[t];
        float d1 = E[(size_t)(g * NGRP + m) * DIMS + t + 256] - cent[t + 256];
        float v = d0 * d0 + d1 * d1;
        #pragma unroll
        for (int off = 32; off > 0; off >>= 1) v += __shfl_down(v, off);
        if ((t & 63) == 0) ws4[t >> 6] = v;
        __syncthreads();
        if (t == 0) {
            float s = ws4[0] + ws4[1] + ws4[2] + ws4[3];
            sumd += (s > 0.0f) ? sqrtf(s) : 0.0f;
        }
        __syncthreads();
    }
    if (t == 0) md[g] = sumd / (float)NGRP;
}

// ---------------- finalize ----------------
__global__ __launch_bounds__(128) void finalize_kernel(const float* __restrict__ acc,
                                                       const float* __restrict__ md,
                                                       float* __restrict__ out) {
    const int t = threadIdx.x;
    __shared__ float w2[2];
    __shared__ float tr_s;
    float v = md[t];
    float s = v;
    #pragma unroll
    for (int off = 32; off > 0; off >>= 1) s += __shfl_down(s, off);
    if ((t & 63) == 0) w2[t >> 6] = s;
    __syncthreads();
    if (t == 0) tr_s = (w2[0] + w2[1]) / 128.0f;
    __syncthreads();
    const float tr = tr_s;
    float dev = fabsf(v / tr - 1.0f);
    #pragma unroll
    for (int off = 32; off > 0; off >>= 1) dev += __shfl_down(dev, off);
    if ((t & 63) == 0) w2[t >> 6] = dev;
    __syncthreads();
    if (t == 0) {
        float penalty = 0.05f * ((w2[0] + w2[1]) / 128.0f);
        float sml = acc[0] / 1575.0f / 8128.0f;   // /(N*N*(N-1)/2)/total_pairs
        out[0] = sml + penalty;
    }
}

__global__ void zero_kernel(float* acc) { *acc = 0.0f; }

extern "C" void kernel_launch(void* const* d_in, const int* in_sizes, int n_in,
                              void* d_out, int out_size, void* d_ws, size_t ws_size,
                              hipStream_t stream) {
    const float* E = (const float*)d_in[0];
    float* out = (float*)d_out;
    char* ws = (char*)d_ws;
    float* acc  = (float*)(ws);             // 1 float
    float* sqn  = (float*)(ws + 256);       // 1920 floats
    float* dAAg = (float*)(ws + 8192);      // 128*225 floats = 115200 B
    float* md   = (float*)(ws + 123648);    // 128 floats
    // total ws use < 125 KB

    zero_kernel<<<1, 1, 0, stream>>>(acc);
    daa_norm_kernel<<<KGRP, 256, 0, stream>>>(E, dAAg, sqn);
    quad_kernel<<<NTILES, 256, 0, stream>>>(E, sqn, dAAg, acc);
    radius_kernel<<<KGRP, 256, 0, stream>>>(E, md);
    finalize_kernel<<<1, 128, 0, stream>>>(acc, md, out);
}